// Round 4
// baseline (407.553 us; speedup 1.0000x reference)
//
#include <hip/hip_runtime.h>
#include <math.h>

// Problem constants (match reference)
#define N_NEU   8192
#define IN_SZ   512
#define OUT_SZ  512
#define N4      (N_NEU / 4)          // 2048 float4 col-quads per row of W_in/synapses
#define OUT4    (OUT_SZ / 4)         // 128 quads per W_out row
#define KPB_SYN 64                   // synapse rows per K1 block
#define KPB_WIN 4                    // W_in rows per K1 block (folded in)
#define TILES   (N_NEU / KPB_SYN)    // 128 partial-sets per stripe (also = IN_SZ/KPB_WIN)
#define K2_KPB  64                   // rows per K2 out-gemv tile
#define OTILES  (N_NEU / K2_KPB)     // 128
constexpr float TAU_INV = 0.1f;
constexpr float G_GAIN  = 1.5f;

// ---------------------------------------------------------------------------
// K1: each block owns 64 synapse rows + 4 W_in rows and one 1024-col stripe.
//     partial[by*8+bx][:] = sum xs[k]*M[k][stripe cols]   (full overwrite, no
//     atomics). Grid = (8,128) = 1024 blocks = exactly 4/CU (perfect balance).
//     by==127 blocks also zero out[0:512] for K2's atomics.
// ---------------------------------------------------------------------------
__global__ __launch_bounds__(256)
void accum_kernel(const float* __restrict__ pot,
                  const float* __restrict__ inputs,
                  const float* __restrict__ synapses,
                  const float* __restrict__ W_in,
                  float4* __restrict__ P4,          // [128*8][256] float4
                  float* __restrict__ out) {
    __shared__ float xs[KPB_SYN + KPB_WIN];         // 68
    const int bx = blockIdx.x, by = blockIdx.y;
    const int tid = threadIdx.x;
    const int ks = by * KPB_SYN;                    // synapse row base
    const int kw = by * KPB_WIN;                    // W_in row base
    if (tid < KPB_SYN)
        xs[tid] = G_GAIN * tanhf(pot[ks + tid]);
    else if (tid < KPB_SYN + KPB_WIN)
        xs[tid] = inputs[kw + (tid - KPB_SYN)];
    if (by == TILES - 1 && tid < 64) out[bx * 64 + tid] = 0.0f;
    __syncthreads();

    const int col4 = bx * 256 + tid;
    const float4* Sp = (const float4*)synapses + (size_t)ks * N4 + col4;
    const float4* Wp = (const float4*)W_in     + (size_t)kw * N4 + col4;

    float4 acc = make_float4(0.f, 0.f, 0.f, 0.f);
#pragma unroll 8
    for (int i = 0; i < KPB_SYN; ++i) {
        float  s = xs[i];
        float4 m = Sp[(size_t)i * N4];
        acc.x = fmaf(s, m.x, acc.x);
        acc.y = fmaf(s, m.y, acc.y);
        acc.z = fmaf(s, m.z, acc.z);
        acc.w = fmaf(s, m.w, acc.w);
    }
#pragma unroll
    for (int i = 0; i < KPB_WIN; ++i) {
        float  s = xs[KPB_SYN + i];
        float4 m = Wp[(size_t)i * N4];
        acc.x = fmaf(s, m.x, acc.x);
        acc.y = fmaf(s, m.y, acc.y);
        acc.z = fmaf(s, m.z, acc.z);
        acc.w = fmaf(s, m.w, acc.w);
    }
    P4[(size_t)(by * 8 + bx) * 256 + tid] = acc;    // coalesced private store
}

// ---------------------------------------------------------------------------
// K2: blocks [0,128):   64-row out-gemv split-K tile — reduce partials for own
//                       rows, pot_new -> tanh -> accumulate out[0:512] (atomics).
//     blocks [128,192): elementwise — reduce partials, pot_new -> d_out[512:].
// block = 128
// ---------------------------------------------------------------------------
__global__ __launch_bounds__(128)
void finish_kernel(const float* __restrict__ pot,
                   const float* __restrict__ P,     // [128*8][1024] floats
                   const float* __restrict__ W_out,
                   float* __restrict__ out) {
    const int b = blockIdx.x;
    const int t = threadIdx.x;
    if (b < OTILES) {
        // ---- out = tanh(pot_new) @ W_out, 64-row split-K tile ----
        __shared__ float xs[K2_KPB];
        const int k0 = b * K2_KPB;
        const int bx = k0 >> 10;                    // 1024-col stripe index
        if (t < K2_KPB) {
            const int off = (k0 & 1023) + t;
            float s = 0.f;
#pragma unroll 8
            for (int by = 0; by < TILES; ++by)
                s += P[(size_t)(by * 8 + bx) * 1024 + off];
            float p  = pot[k0 + t];
            float pn = p + (s - p) * TAU_INV;
            xs[t] = tanhf(pn);
        }
        __syncthreads();

        const float4* Wp = (const float4*)W_out + (size_t)k0 * OUT4 + t;
        float4 acc = make_float4(0.f, 0.f, 0.f, 0.f);
#pragma unroll 8
        for (int i = 0; i < K2_KPB; ++i) {
            float  sx = xs[i];
            float4 m  = Wp[(size_t)i * OUT4];
            acc.x = fmaf(sx, m.x, acc.x);
            acc.y = fmaf(sx, m.y, acc.y);
            acc.z = fmaf(sx, m.z, acc.z);
            acc.w = fmaf(sx, m.w, acc.w);
        }
        float* op = out + (size_t)t * 4;
        atomicAdd(op + 0, acc.x);
        atomicAdd(op + 1, acc.y);
        atomicAdd(op + 2, acc.z);
        atomicAdd(op + 3, acc.w);
    } else {
        // ---- pot_new elementwise -> d_out[512:] ----
        const int j   = (b - OTILES) * 128 + t;
        const int bx  = j >> 10;
        const int off = j & 1023;
        float s = 0.f;
#pragma unroll 8
        for (int by = 0; by < TILES; ++by)
            s += P[(size_t)(by * 8 + bx) * 1024 + off];
        float p  = pot[j];
        float pn = p + (s - p) * TAU_INV;
        out[OUT_SZ + j] = pn;
    }
}

// ---------------------------------------------------------------------------
extern "C" void kernel_launch(void* const* d_in, const int* in_sizes, int n_in,
                              void* d_out, int out_size, void* d_ws, size_t ws_size,
                              hipStream_t stream) {
    const float* inputs   = (const float*)d_in[0];   // [512]
    const float* pot      = (const float*)d_in[1];   // [8192]
    const float* W_in     = (const float*)d_in[2];   // [512, 8192]
    const float* synapses = (const float*)d_in[3];   // [8192, 8192]
    const float* W_out    = (const float*)d_in[4];   // [8192, 512]

    float* out = (float*)d_out;          // [0:512] output, [512:8704] pot_new
    float* P   = (float*)d_ws;           // 128*8*1024 floats = 4 MB partials

    // K1: 8 col-stripes x 128 tiles (64 syn + 4 W_in rows each), no atomics
    accum_kernel<<<dim3(8, TILES), dim3(256), 0, stream>>>(
        pot, inputs, synapses, W_in, (float4*)P, out);

    // K2: 128 out-gemv tiles + 64 elementwise blocks
    finish_kernel<<<dim3(OTILES + N_NEU / 128), dim3(128), 0, stream>>>(
        pot, P, W_out, out);
}